// Round 4
// baseline (567.495 us; speedup 1.0000x reference)
//
#include <hip/hip_runtime.h>

#define NPTS  262144
#define NV    6890
#define NVP   6896            // padded to multiple of 8
#define NPAIR (NVP/2)         // 3448 pairs, multiple of 4
#define NJ    24

typedef float f32x2 __attribute__((ext_vector_type(2)));

// Pack vertex pairs SoA-style for packed-fp32 distance math:
// per pair p (verts a=2p, b=2p+1), 8 floats:
//   [-2xa, -2xb, -2ya, -2yb, -2za, -2zb, |va|^2, |vb|^2]
// |v|^2 in numpy's rounding order: (x*x + y*y) + z*z.
__global__ void pack_pairs_kernel(const float* __restrict__ verts, float* __restrict__ pp) {
    int p = blockIdx.x * 256 + threadIdx.x;
    if (p >= NPAIR) return;
    int a = 2 * p, b = 2 * p + 1;
    float xa = 0.f, ya = 0.f, za = 0.f, sa = 3.0e37f;
    float xb = 0.f, yb = 0.f, zb = 0.f, sb = 3.0e37f;
    if (a < NV) {
        xa = verts[3*a+0]; ya = verts[3*a+1]; za = verts[3*a+2];
        sa = __fadd_rn(__fadd_rn(__fmul_rn(xa,xa), __fmul_rn(ya,ya)), __fmul_rn(za,za));
    }
    if (b < NV) {
        xb = verts[3*b+0]; yb = verts[3*b+1]; zb = verts[3*b+2];
        sb = __fadd_rn(__fadd_rn(__fmul_rn(xb,xb), __fmul_rn(yb,yb)), __fmul_rn(zb,zb));
    }
    float* o = pp + (size_t)p * 8;
    o[0] = -2.f*xa; o[1] = -2.f*xb;
    o[2] = -2.f*ya; o[3] = -2.f*yb;
    o[4] = -2.f*za; o[5] = -2.f*zb;
    o[6] = sa;      o[7] = sb;
}

// Packed-fp32 KNN + blend. Distance compared: d~ = |v|^2 - 2 q.v  (argmin-equivalent,
// per-query constant |q|^2 dropped). v_pk_fma_f32 does 2 verts per instruction.
template<int PACKED>
__global__ __launch_bounds__(256)
void knn_blend_kernel(const float* __restrict__ qpts,
                      const float* __restrict__ pp,
                      const float* __restrict__ verts,
                      const float* __restrict__ weights,
                      const float* __restrict__ At,
                      const float* __restrict__ Ab,
                      float* __restrict__ out)
{
    __shared__ float sAt[NJ*16];
    __shared__ float sAb[NJ*16];
    const int tid = threadIdx.x;
    for (int i = tid; i < NJ*16; i += 256) { sAt[i] = At[i]; sAb[i] = Ab[i]; }

    const int n = blockIdx.x * 256 + tid;
    const float q0 = qpts[3*n+0], q1 = qpts[3*n+1], q2 = qpts[3*n+2];

    int bi = 0;

    if (PACKED) {
        const float4* pp4 = (const float4*)pp;
        const f32x2 q00 = {q0, q0}, q11 = {q1, q1}, q22 = {q2, q2};
        float bLo = 3.4e38f, bHi = 3.4e38f;
        int   iLo = 0,       iHi = 1;
        for (int p = 0; p < NPAIR; p += 4) {
            // load 4 pair-records (8 x float4)
            float4 A0 = pp4[2*p+0], B0 = pp4[2*p+1];
            float4 A1 = pp4[2*p+2], B1 = pp4[2*p+3];
            float4 A2 = pp4[2*p+4], B2 = pp4[2*p+5];
            float4 A3 = pp4[2*p+6], B3 = pp4[2*p+7];
#pragma unroll
            for (int j = 0; j < 4; ++j) {
                float4 A = (j==0)?A0:(j==1)?A1:(j==2)?A2:A3;
                float4 B = (j==0)?B0:(j==1)?B1:(j==2)?B2:B3;
                f32x2 X2 = {A.x, A.y};    // -2x pair
                f32x2 Y2 = {A.z, A.w};    // -2y pair
                f32x2 Z2 = {B.x, B.y};    // -2z pair
                f32x2 S2 = {B.z, B.w};    // |v|^2 pair
                f32x2 d2;
                asm("v_pk_fma_f32 %0, %2, %3, %1\n\t"   // d2 = Z2*q2 + S2
                    "v_pk_fma_f32 %0, %4, %5, %0\n\t"   // d2 = Y2*q1 + d2
                    "v_pk_fma_f32 %0, %6, %7, %0"       // d2 = X2*q0 + d2
                    : "=&v"(d2)
                    : "v"(S2), "v"(Z2), "v"(q22),
                      "v"(Y2), "v"(q11), "v"(X2), "v"(q00));
                const float dA = d2.x, dB = d2.y;
                const int ia = 2*(p+j), ib = ia + 1;
                bool la = dA < bLo;  bLo = la ? dA : bLo;  iLo = la ? ia : iLo;
                bool lb = dB < bHi;  bHi = lb ? dB : bHi;  iHi = lb ? ib : iHi;
            }
        }
        // merge halves; exact tie -> smaller index (numpy first-occurrence)
        if (bHi < bLo)      bi = iHi;
        else if (bLo < bHi) bi = iLo;
        else                bi = (iLo < iHi) ? iLo : iHi;
    } else {
        // fallback (no workspace): direct scan, reference-shaped rounding
        const float qsq = __fadd_rn(__fadd_rn(__fmul_rn(q0,q0), __fmul_rn(q1,q1)), __fmul_rn(q2,q2));
        float best = 3.4e38f;
        for (int v = 0; v < NV; ++v) {
            float vx = verts[3*v+0], vy = verts[3*v+1], vz = verts[3*v+2];
            float vs = __fadd_rn(__fadd_rn(__fmul_rn(vx,vx), __fmul_rn(vy,vy)), __fmul_rn(vz,vz));
            float t = fmaf(q2, vz, fmaf(q1, vy, __fmul_rn(q0, vx)));
            float d = __fadd_rn(__fsub_rn(qsq, __fadd_rn(t, t)), vs);
            bool lt = d < best;
            best = lt ? d : best;
            bi   = lt ? v : bi;
        }
    }

    __syncthreads();   // sAt/sAb ready

    // Blend the two transform stacks with the gathered weight row (rows 0..2 only).
    const float* wrow = weights + bi * NJ;
    float M1[12], M2[12];
#pragma unroll
    for (int i = 0; i < 12; ++i) { M1[i] = 0.f; M2[i] = 0.f; }
    for (int k = 0; k < NJ; ++k) {
        const float w = wrow[k];
        const float* a = sAt + k*16;
        const float* b = sAb + k*16;
#pragma unroll
        for (int i = 0; i < 12; ++i) {
            M1[i] = fmaf(w, a[i], M1[i]);
            M2[i] = fmaf(w, b[i], M2[i]);
        }
    }

    // can = inv(M1[:3,:3]) @ (q - M1[:,3])  via adjugate/det (well-conditioned)
    float p0 = q0 - M1[3], p1 = q1 - M1[7], p2 = q2 - M1[11];
    float a_=M1[0], b_=M1[1], c_=M1[2];
    float d_=M1[4], e_=M1[5], f_=M1[6];
    float g_=M1[8], h_=M1[9], i_=M1[10];
    float A0 = e_*i_ - f_*h_, A1 = c_*h_ - b_*i_, A2 = b_*f_ - c_*e_;
    float A3 = f_*g_ - d_*i_, A4 = a_*i_ - c_*g_, A5 = c_*d_ - a_*f_;
    float A6 = d_*h_ - e_*g_, A7 = b_*g_ - a_*h_, A8 = a_*e_ - b_*d_;
    float det  = a_*A0 + b_*A3 + c_*A6;
    float rdet = 1.0f / det;
    float x0 = (A0*p0 + A1*p1 + A2*p2) * rdet;
    float x1 = (A3*p0 + A4*p1 + A5*p2) * rdet;
    float x2 = (A6*p0 + A7*p1 + A8*p2) * rdet;

    // out = M2[:3,:3] @ can + M2[:,3]
    float o0 = fmaf(M2[0],x0, fmaf(M2[1],x1, fmaf(M2[2], x2, M2[3])));
    float o1 = fmaf(M2[4],x0, fmaf(M2[5],x1, fmaf(M2[6], x2, M2[7])));
    float o2 = fmaf(M2[8],x0, fmaf(M2[9],x1, fmaf(M2[10],x2, M2[11])));

    out[3*n+0] = o0; out[3*n+1] = o1; out[3*n+2] = o2;
}

extern "C" void kernel_launch(void* const* d_in, const int* in_sizes, int n_in,
                              void* d_out, int out_size, void* d_ws, size_t ws_size,
                              hipStream_t stream) {
    const float* qpts    = (const float*)d_in[0];
    const float* verts   = (const float*)d_in[1];
    const float* weights = (const float*)d_in[2];
    const float* At      = (const float*)d_in[3];
    const float* Ab      = (const float*)d_in[4];
    float* out = (float*)d_out;

    const size_t need = (size_t)NPAIR * 8 * sizeof(float);
    if (ws_size >= need) {
        float* pp = (float*)d_ws;
        pack_pairs_kernel<<<(NPAIR + 255) / 256, 256, 0, stream>>>(verts, pp);
        knn_blend_kernel<1><<<NPTS / 256, 256, 0, stream>>>(qpts, pp, verts, weights, At, Ab, out);
    } else {
        knn_blend_kernel<0><<<NPTS / 256, 256, 0, stream>>>(qpts, nullptr, verts, weights, At, Ab, out);
    }
}

// Round 5
// 364.270 us; speedup vs baseline: 1.5579x; 1.5579x over previous
//
#include <hip/hip_runtime.h>

#define NPTS  262144
#define NV    6890
#define NVP   6896          // padded to multiple of 8
#define NJ    24
#define TILE  1724          // NVP/4 verts per LDS tile (27.6 KB)
#define NTILE 4

// Pack verts as [-2x, -2y, -2z, |v|^2]: distance reduces to a pure 3-FMA chain
// d~ = |v|^2 - 2 q.v  (argmin-equivalent; per-query |q|^2 constant dropped).
// |v|^2 in numpy's rounding order: (x*x + y*y) + z*z.
__global__ void pack_verts_kernel(const float* __restrict__ verts, float4* __restrict__ vp) {
    int v = blockIdx.x * 256 + threadIdx.x;
    if (v >= NVP) return;
    if (v < NV) {
        float x = verts[3*v+0], y = verts[3*v+1], z = verts[3*v+2];
        float vs = __fadd_rn(__fadd_rn(__fmul_rn(x,x), __fmul_rn(y,y)), __fmul_rn(z,z));
        vp[v] = make_float4(-2.f*x, -2.f*y, -2.f*z, vs);
    } else {
        // pad: huge-but-finite distance, never selected
        vp[v] = make_float4(0.f, 0.f, 0.f, 3.0e37f);
    }
}

template<int PACKED>
__global__ __launch_bounds__(256)
void knn_blend_kernel(const float* __restrict__ qpts,
                      const float4* __restrict__ vp,
                      const float* __restrict__ verts,
                      const float* __restrict__ weights,
                      const float* __restrict__ At,
                      const float* __restrict__ Ab,
                      float* __restrict__ out)
{
    __shared__ float4 sv[TILE];
    __shared__ float  sAt[NJ*16];
    __shared__ float  sAb[NJ*16];
    const int tid = threadIdx.x;
    for (int i = tid; i < NJ*16; i += 256) { sAt[i] = At[i]; sAb[i] = Ab[i]; }

    const int n = blockIdx.x * 256 + tid;
    const float q0 = qpts[3*n+0], q1 = qpts[3*n+1], q2 = qpts[3*n+2];

    float best = 3.4e38f;
    int   bi   = 0;

    if (PACKED) {
        for (int t = 0; t < NTILE; ++t) {
            const int tb = t * TILE;
            __syncthreads();                       // previous-tile readers done
            for (int i = tid; i < TILE; i += 256)  // cooperative stage, float4
                sv[i] = vp[tb + i];
            __syncthreads();
#pragma unroll 4
            for (int u = 0; u < TILE; ++u) {
                const float4 vv = sv[u];           // wave-uniform addr -> broadcast
                // same fma-chain order as the round-4 passing kernel
                const float d = fmaf(vv.x, q0, fmaf(vv.y, q1, fmaf(vv.z, q2, vv.w)));
                const int cand = tb + u;           // uniform -> SALU
                const bool lt = d < best;          // strict < = first-occurrence argmin
                best = lt ? d : best;
                bi   = lt ? cand : bi;
            }
        }
    } else {
        // fallback (no workspace): direct scan, reference-shaped rounding
        const float qsq = __fadd_rn(__fadd_rn(__fmul_rn(q0,q0), __fmul_rn(q1,q1)), __fmul_rn(q2,q2));
        for (int v = 0; v < NV; ++v) {
            float vx = verts[3*v+0], vy = verts[3*v+1], vz = verts[3*v+2];
            float vs = __fadd_rn(__fadd_rn(__fmul_rn(vx,vx), __fmul_rn(vy,vy)), __fmul_rn(vz,vz));
            float tq = fmaf(q2, vz, fmaf(q1, vy, __fmul_rn(q0, vx)));
            float d  = __fadd_rn(__fsub_rn(qsq, __fadd_rn(tq, tq)), vs);
            bool lt = d < best;
            best = lt ? d : best;
            bi   = lt ? v : bi;
        }
        __syncthreads();   // sAt/sAb ready
    }

    // Blend the two transform stacks with the gathered weight row (rows 0..2 only).
    const float* wrow = weights + bi * NJ;
    float M1[12], M2[12];
#pragma unroll
    for (int i = 0; i < 12; ++i) { M1[i] = 0.f; M2[i] = 0.f; }
    for (int k = 0; k < NJ; ++k) {
        const float w = wrow[k];
        const float* a = sAt + k*16;
        const float* b = sAb + k*16;
#pragma unroll
        for (int i = 0; i < 12; ++i) {
            M1[i] = fmaf(w, a[i], M1[i]);
            M2[i] = fmaf(w, b[i], M2[i]);
        }
    }

    // can = inv(M1[:3,:3]) @ (q - M1[:,3])  via adjugate/det (well-conditioned)
    float p0 = q0 - M1[3], p1 = q1 - M1[7], p2 = q2 - M1[11];
    float a_=M1[0], b_=M1[1], c_=M1[2];
    float d_=M1[4], e_=M1[5], f_=M1[6];
    float g_=M1[8], h_=M1[9], i_=M1[10];
    float A0 = e_*i_ - f_*h_, A1 = c_*h_ - b_*i_, A2 = b_*f_ - c_*e_;
    float A3 = f_*g_ - d_*i_, A4 = a_*i_ - c_*g_, A5 = c_*d_ - a_*f_;
    float A6 = d_*h_ - e_*g_, A7 = b_*g_ - a_*h_, A8 = a_*e_ - b_*d_;
    float det  = a_*A0 + b_*A3 + c_*A6;
    float rdet = 1.0f / det;
    float x0 = (A0*p0 + A1*p1 + A2*p2) * rdet;
    float x1 = (A3*p0 + A4*p1 + A5*p2) * rdet;
    float x2 = (A6*p0 + A7*p1 + A8*p2) * rdet;

    // out = M2[:3,:3] @ can + M2[:,3]
    float o0 = fmaf(M2[0],x0, fmaf(M2[1],x1, fmaf(M2[2], x2, M2[3])));
    float o1 = fmaf(M2[4],x0, fmaf(M2[5],x1, fmaf(M2[6], x2, M2[7])));
    float o2 = fmaf(M2[8],x0, fmaf(M2[9],x1, fmaf(M2[10],x2, M2[11])));

    out[3*n+0] = o0; out[3*n+1] = o1; out[3*n+2] = o2;
}

extern "C" void kernel_launch(void* const* d_in, const int* in_sizes, int n_in,
                              void* d_out, int out_size, void* d_ws, size_t ws_size,
                              hipStream_t stream) {
    const float* qpts    = (const float*)d_in[0];
    const float* verts   = (const float*)d_in[1];
    const float* weights = (const float*)d_in[2];
    const float* At      = (const float*)d_in[3];
    const float* Ab      = (const float*)d_in[4];
    float* out = (float*)d_out;

    const size_t need = (size_t)NVP * sizeof(float4);
    if (ws_size >= need) {
        float4* vp = (float4*)d_ws;
        pack_verts_kernel<<<(NVP + 255) / 256, 256, 0, stream>>>(verts, vp);
        knn_blend_kernel<1><<<NPTS / 256, 256, 0, stream>>>(qpts, vp, verts, weights, At, Ab, out);
    } else {
        knn_blend_kernel<0><<<NPTS / 256, 256, 0, stream>>>(qpts, nullptr, verts, weights, At, Ab, out);
    }
}